// Round 4
// baseline (1379.352 us; speedup 1.0000x reference)
//
#include <hip/hip_runtime.h>
#include <hip/hip_bf16.h>

// ScaledDotProductAttention: B=2,H=16,S=2048,D=64 -> (output[B,H,S,D], weights[B,H,S,S]).
// Inputs float32 (proven: bf16 misread -> NaN), outputs FLOAT32 (reference dtype; R0-R2 wrote
// bf16 into a float* buffer -> decorrelated-same-magnitude absmax ~0.52, now fixed).
// Two-pass flash-with-weights, bf16 MFMA 16x16x32 for QK^T and PV, fp32 softmax & stores.
// Mask element encoding runtime-detected: uint8 / int32 / float32 / bf16 -> single byte test.

namespace {

constexpr int kS = 2048;
constexpr int kD = 64;
constexpr int kBH = 32;            // B*H
constexpr int kTQW = 32;           // q rows per wave
constexpr int kNW = 4;             // waves per block
constexpr int kTQB = kTQW * kNW;   // 128 q rows per block
constexpr int kChunk = 64;         // k rows per chunk
constexpr size_t kWOff = (size_t)kBH * kS * kD;  // weights offset in d_out (4194304 elems)

typedef __attribute__((ext_vector_type(8))) short bf16x8;
typedef __attribute__((ext_vector_type(4))) float f32x4;

__device__ inline short f2bf(float f) {
  union { float f; unsigned u; } x; x.f = f;
  return (short)((x.u + 0x7fffu + ((x.u >> 16) & 1u)) >> 16);  // RNE
}

__device__ inline bf16x8 load8_bf16(const float* p, float scale) {
  float4 x0 = *(const float4*)p;
  float4 x1 = *(const float4*)(p + 4);
  bf16x8 f;
  f[0] = f2bf(x0.x * scale); f[1] = f2bf(x0.y * scale);
  f[2] = f2bf(x0.z * scale); f[3] = f2bf(x0.w * scale);
  f[4] = f2bf(x1.x * scale); f[5] = f2bf(x1.y * scale);
  f[6] = f2bf(x1.z * scale); f[7] = f2bf(x1.w * scale);
  return f;
}

__global__ __launch_bounds__(256) void attn_fused(
    const float* __restrict__ qg, const float* __restrict__ kg,
    const float* __restrict__ vg, const unsigned int* __restrict__ mg,
    float* __restrict__ outg) {
  __shared__ __align__(16) short Vt[kD][72];          // V^T chunk: [d][krel], bf16
  __shared__ __align__(16) short Wt[kNW][kTQW][72];   // per-wave weights: [qlocal][krel], bf16

  const int tid  = threadIdx.x;
  const int wv   = tid >> 6;
  const int lane = tid & 63;
  const int l15  = lane & 15;
  const int quad = lane >> 4;

  const int bid = blockIdx.x;       // 512 blocks = 32 bh * 16 qtiles
  const int qt  = bid & 15;
  const int bh  = bid >> 4;
  const int b   = bh >> 4;          // H = 16
  const int q0  = qt * kTQB + wv * kTQW;

  // ---- mask encoding detection from first 64 words (in-bounds for all candidates) ----
  // uint8 bools (raw numpy) | int32 0/1 | float32 0/1.0 | bf16 0/1.0
  // Unified read: masked <=> byte at (elem*msz + hib) != 0.
  //   uint8: msz=1 hib=0; int32: msz=4 hib=0 (byte0=1); bf16: msz=2 hib=0 (byte0=0x80);
  //   float32: msz=4 hib=3 (1.0f bytes [0,0,0x80,0x3F], byte0==0 -> need high byte).
  int allW32 = 1, allI32 = 1, allBF = 1;
#pragma unroll
  for (int i = 0; i < 64; ++i) {
    const unsigned u = mg[i];
    const unsigned lo = u & 0xFFFFu, hi = u >> 16;
    allW32 &= (int)(u == 0u || u == 0x3F800000u);
    allI32 &= (int)(u == 0u || u == 1u);
    allBF  &= (int)((lo == 0u || lo == 0x3F80u) && (hi == 0u || hi == 0x3F80u));
  }
  int msz, hib;
  if (allI32)      { msz = 4; hib = 0; }   // int32 0/1
  else if (allW32) { msz = 4; hib = 3; }   // float32 0/1.0 (checked before allBF superset case)
  else if (allBF)  { msz = 2; hib = 0; }   // bf16 0/1.0
  else             { msz = 1; hib = 0; }   // packed uint8 bools
  const unsigned char* mbase =
      (const unsigned char*)mg + (size_t)b * kS * kS * msz + hib;
  const int mshift = (msz == 4) ? 2 : (msz == 2) ? 1 : 0;

  const float* qbase = qg + (size_t)bh * kS * kD;
  const float* kbase = kg + (size_t)bh * kS * kD;
  const float* vbase = vg + (size_t)bh * kS * kD;
  float* obase = outg + (size_t)bh * kS * kD;
  float* wbase = outg + kWOff + (size_t)bh * kS * kS;

  // ---- Q A-fragments, pre-scaled by 1/8 (exact in fp32), kept in registers ----
  // A layout: lane holds A[m=l15][k = quad*8 + j]
  bf16x8 aq[2][2];
#pragma unroll
  for (int rg = 0; rg < 2; ++rg)
#pragma unroll
    for (int dh = 0; dh < 2; ++dh)
      aq[rg][dh] = load8_bf16(qbase + (size_t)(q0 + rg * 16 + l15) * kD + dh * 32 + quad * 8, 0.125f);

  // ================= Pass A: l = sum_k exp(s) per q row =================
  float lsum[2][4];
#pragma unroll
  for (int rg = 0; rg < 2; ++rg)
#pragma unroll
    for (int r = 0; r < 4; ++r) lsum[rg][r] = 0.f;

  for (int k0 = 0; k0 < kS; k0 += kChunk) {
#pragma unroll
    for (int cg = 0; cg < 4; ++cg) {
      const int krow = k0 + cg * 16 + l15;   // B layout: lane holds B[k=quad*8+j][n=l15]
      bf16x8 bk0 = load8_bf16(kbase + (size_t)krow * kD + quad * 8, 1.0f);
      bf16x8 bk1 = load8_bf16(kbase + (size_t)krow * kD + 32 + quad * 8, 1.0f);
#pragma unroll
      for (int rg = 0; rg < 2; ++rg) {
        f32x4 acc = {0.f, 0.f, 0.f, 0.f};
        acc = __builtin_amdgcn_mfma_f32_16x16x32_bf16(aq[rg][0], bk0, acc, 0, 0, 0);
        acc = __builtin_amdgcn_mfma_f32_16x16x32_bf16(aq[rg][1], bk1, acc, 0, 0, 0);
        // C/D layout: lane holds S[row = quad*4 + r][col = l15]
        const int kcol = k0 + cg * 16 + l15;
#pragma unroll
        for (int r = 0; r < 4; ++r) {
          const int qrow = q0 + rg * 16 + quad * 4 + r;
          const size_t off = (size_t)qrow * kS + kcol;
          const bool masked = mbase[off << mshift] != 0;
          const float s = masked ? -1e-9f : acc[r];
          lsum[rg][r] += __expf(s);
        }
      }
    }
  }

  // reduce row sums across the 16 lanes (same quad) holding that row's columns
  float inv_l[2][4];
#pragma unroll
  for (int rg = 0; rg < 2; ++rg)
#pragma unroll
    for (int r = 0; r < 4; ++r) {
      float t = lsum[rg][r];
      t += __shfl_xor(t, 1, 16);
      t += __shfl_xor(t, 2, 16);
      t += __shfl_xor(t, 4, 16);
      t += __shfl_xor(t, 8, 16);
      inv_l[rg][r] = 1.0f / t;
    }

  // ================= Pass B: weights out (fp32) + PV =================
  f32x4 acco[2][4];
#pragma unroll
  for (int rg = 0; rg < 2; ++rg)
#pragma unroll
    for (int dcg = 0; dcg < 4; ++dcg) acco[rg][dcg] = (f32x4){0.f, 0.f, 0.f, 0.f};

  for (int k0 = 0; k0 < kS; k0 += kChunk) {
    __syncthreads();  // previous chunk's PV reads of Vt complete
    // ---- stage V^T chunk (bf16) cooperatively: Vt[d][krel] = V[k0+krel][d] ----
    {
      const int vr = tid >> 2;           // krel 0..63
      const int vc = (tid & 3) * 16;     // d group
      const float* p = vbase + (size_t)(k0 + vr) * kD + vc;
#pragma unroll
      for (int i = 0; i < 4; ++i) {
        float4 x = *(const float4*)(p + 4 * i);
        Vt[vc + 4 * i + 0][vr] = f2bf(x.x);
        Vt[vc + 4 * i + 1][vr] = f2bf(x.y);
        Vt[vc + 4 * i + 2][vr] = f2bf(x.z);
        Vt[vc + 4 * i + 3][vr] = f2bf(x.w);
      }
    }
    // ---- recompute scores, emit normalized fp32 weights ----
#pragma unroll
    for (int cg = 0; cg < 4; ++cg) {
      const int krow = k0 + cg * 16 + l15;
      bf16x8 bk0 = load8_bf16(kbase + (size_t)krow * kD + quad * 8, 1.0f);
      bf16x8 bk1 = load8_bf16(kbase + (size_t)krow * kD + 32 + quad * 8, 1.0f);
#pragma unroll
      for (int rg = 0; rg < 2; ++rg) {
        f32x4 acc = {0.f, 0.f, 0.f, 0.f};
        acc = __builtin_amdgcn_mfma_f32_16x16x32_bf16(aq[rg][0], bk0, acc, 0, 0, 0);
        acc = __builtin_amdgcn_mfma_f32_16x16x32_bf16(aq[rg][1], bk1, acc, 0, 0, 0);
        const int kcol = k0 + cg * 16 + l15;
#pragma unroll
        for (int r = 0; r < 4; ++r) {
          const int qrow = q0 + rg * 16 + quad * 4 + r;
          const size_t off = (size_t)qrow * kS + kcol;
          const bool masked = mbase[off << mshift] != 0;
          const float s = masked ? -1e-9f : acc[r];
          const float w = __expf(s) * inv_l[rg][r];
          wbase[off] = w;                                           // fp32 weights
          Wt[wv][rg * 16 + quad * 4 + r][cg * 16 + l15] = f2bf(w);  // bf16 for PV
        }
      }
    }
    __syncthreads();  // Vt staged + Wt written
    // ---- PV: O += W (A) x V (B) ----
#pragma unroll
    for (int ks = 0; ks < 2; ++ks) {
      bf16x8 bv[4];
#pragma unroll
      for (int dcg = 0; dcg < 4; ++dcg)
        bv[dcg] = *(const bf16x8*)&Vt[dcg * 16 + l15][ks * 32 + quad * 8];
#pragma unroll
      for (int rg = 0; rg < 2; ++rg) {
        bf16x8 aw = *(const bf16x8*)&Wt[wv][rg * 16 + l15][ks * 32 + quad * 8];
#pragma unroll
        for (int dcg = 0; dcg < 4; ++dcg)
          acco[rg][dcg] = __builtin_amdgcn_mfma_f32_16x16x32_bf16(aw, bv[dcg], acco[rg][dcg], 0, 0, 0);
      }
    }
  }

  // ---- epilogue: store O (fp32) ----
#pragma unroll
  for (int rg = 0; rg < 2; ++rg)
#pragma unroll
    for (int dcg = 0; dcg < 4; ++dcg)
#pragma unroll
      for (int r = 0; r < 4; ++r)
        obase[(size_t)(q0 + rg * 16 + quad * 4 + r) * kD + dcg * 16 + l15] = acco[rg][dcg][r];
}

}  // namespace

extern "C" void kernel_launch(void* const* d_in, const int* in_sizes, int n_in,
                              void* d_out, int out_size, void* d_ws, size_t ws_size,
                              hipStream_t stream) {
  const float* q = (const float*)d_in[0];
  const float* k = (const float*)d_in[1];
  const float* v = (const float*)d_in[2];
  const unsigned int* mask = (const unsigned int*)d_in[3];
  float* out = (float*)d_out;  // fp32 output buffer (output ++ weights)
  attn_fused<<<dim3(kBH * (kS / kTQB)), dim3(256), 0, stream>>>(q, k, v, mask, out);
}